// Round 9
// baseline (59.335 us; speedup 1.0000x reference)
//
#include <hip/hip_runtime.h>
#include <stdint.h>

#define NB   8
#define NC   256
#define NT   1024
#define NM   512
#define NNEG 100

typedef unsigned short u16;
typedef unsigned long long u64;
typedef __attribute__((ext_vector_type(8))) short bf16x8;
typedef __attribute__((ext_vector_type(4))) float f32x4;

// wave-level LDS visibility fence (proven in R8)
#define WAVE_LDS_FENCE() asm volatile("s_waitcnt lgkmcnt(0)" ::: "memory")

// ---------------- Threefry-2x32-20 (JAX) ----------------
__device__ __forceinline__ unsigned rotl32(unsigned x, int d) {
  return (x << d) | (x >> (32 - d));
}

__device__ unsigned threefry_bits(unsigned i) {
  const unsigned half = 1048576u; // 2^20
  const bool lo = i < half;
  unsigned v0 = lo ? i : (i - half);
  unsigned v1 = lo ? (i + half) : i;
  const unsigned k0 = 0u, k1 = 42u;
  const unsigned k2 = k0 ^ k1 ^ 0x1BD11BDAu;
  v0 += k0; v1 += k1;
#define TF_R(r) { v0 += v1; v1 = rotl32(v1, r); v1 ^= v0; }
  TF_R(13) TF_R(15) TF_R(26) TF_R(6)
  v0 += k1; v1 += k2 + 1u;
  TF_R(17) TF_R(29) TF_R(16) TF_R(24)
  v0 += k2; v1 += k0 + 2u;
  TF_R(13) TF_R(15) TF_R(26) TF_R(6)
  v0 += k0; v1 += k1 + 3u;
  TF_R(17) TF_R(29) TF_R(16) TF_R(24)
  v0 += k1; v1 += k2 + 4u;
  TF_R(13) TF_R(15) TF_R(26) TF_R(6)
  v0 += k2; v1 += k0 + 5u;
#undef TF_R
  return lo ? v0 : v1;
}

// ---------------- Kernel 1: compact + bf16 (RTN) ----------------
// Proven R4/R8 structure, single bf16 plane per matrix; also zeroes the
// fused kernel's completion counter (kernel boundary = device-wide fence).
__global__ __launch_bounds__(256) void k_compact(const float* __restrict__ ctx,
                                                 const float* __restrict__ feat,
                                                 const void* __restrict__ maskp,
                                                 u16* __restrict__ MC, u16* __restrict__ MF,
                                                 int* __restrict__ counter) {
  __shared__ float lds[64][129];
  __shared__ int posl[128];
  __shared__ int wsum[4];
  __shared__ int det[3];
  const int tid = threadIdx.x;
  const int lane = tid & 63, wid = tid >> 6;
  const int t0 = blockIdx.x * 128;
  const int b = blockIdx.y >> 1, mat = blockIdx.y & 1;
  const unsigned char* mb = (const unsigned char*)maskp;

  if (blockIdx.x == 0 && blockIdx.y == 0 && tid == 0) *counter = 0;

  if (tid < 3) det[tid] = 0;
  __syncthreads();
  {
    int c1 = 0, c4 = 0, c8 = 0;
    for (int j = tid; j < 1024; j += 256) {
      c1 += (mb[j] != 0);
      c4 += (((const unsigned*)mb)[j] != 0u);
      c8 += (((const u64*)mb)[j] != 0ull);
    }
#pragma unroll
    for (int off = 32; off; off >>= 1) {
      c1 += __shfl_xor(c1, off, 64);
      c4 += __shfl_xor(c4, off, 64);
      c8 += __shfl_xor(c8, off, 64);
    }
    if (lane == 0) { atomicAdd(&det[0], c1); atomicAdd(&det[1], c4); atomicAdd(&det[2], c8); }
  }
  __syncthreads();
  const int stride = (det[1] == 512) ? 4 : ((det[0] == 512) ? 1 : ((det[2] == 512) ? 8 : 4));

  int f4[4]; int s = 0;
#pragma unroll
  for (int j = 0; j < 4; ++j) {
    int tt = 4 * tid + j;
    size_t e = (size_t)b * NT + tt;
    int f;
    if (stride == 1)      f = (mb[e] != 0);
    else if (stride == 4) f = (((const unsigned*)mb)[e] != 0u);
    else                  f = (((const u64*)mb)[e] != 0ull);
    f4[j] = f; s += f;
  }
  int incl = s;
#pragma unroll
  for (int off = 1; off < 64; off <<= 1) {
    int o = __shfl_up(incl, off, 64);
    if (lane >= off) incl += o;
  }
  if (lane == 63) wsum[wid] = incl;
  __syncthreads();
  int wbase = 0;
#pragma unroll
  for (int w = 0; w < 4; ++w) if (w < wid) wbase += wsum[w];
  int excl = wbase + incl - s;
#pragma unroll
  for (int j = 0; j < 4; ++j) {
    int tt = 4 * tid + j;
    if (tt >= t0 && tt < t0 + 128) posl[tt - t0] = f4[j] ? excl : -1;
    excl += f4[j];
  }

  const float* src = (mat ? feat : ctx) + (size_t)b * NC * NT;
  u16* dst = (mat ? MF : MC) + (size_t)b * NM * NC;

  const int c4i = tid >> 6, tl = tid & 63, tr = tid >> 6;
  for (int chunk = 0; chunk < 4; ++chunk) {
    int c0 = chunk * 64;
    __syncthreads();
    for (int ci = 0; ci < 16; ++ci) {
      int cc = c4i * 16 + ci;
#pragma unroll
      for (int tj = 0; tj < 2; ++tj) {
        int tt = tl + 64 * tj;
        lds[cc][tt] = src[(size_t)(c0 + cc) * NT + t0 + tt];
      }
    }
    __syncthreads();
    for (int tt = tr; tt < 128; tt += 4) {
      int p = posl[tt];
      if (p >= 0) {
        unsigned xb = __float_as_uint(lds[tl][tt]);
        xb += 0x7FFFu + ((xb >> 16) & 1u);   // round-to-nearest-even bf16
        dst[(size_t)p * NC + c0 + tl] = (u16)(xb >> 16);
      }
    }
  }
}

// ---------------- Kernel 2: fused strip-GEMM + selection + loss + reduce ----
// 256 blocks (1/CU) x 256 thr. Block = (b, 16-row strip m0..m0+15) x all 512
// cols: A-frags in regs (global), B-frags streamed from L2-hot MF, S kept in
// LDS; then proven fenced wave-selection/softmax (4 rows/wave); last-block
// fixed-order reduction -> out (bitwise deterministic).
__global__ __launch_bounds__(256) void k_fused(const u16* __restrict__ MC,
                                               const u16* __restrict__ MF,
                                               float* __restrict__ partials,
                                               int* __restrict__ counter,
                                               float* __restrict__ out) {
  __shared__ float S_lds[16][516];            // 33 KB, pitch 516 (bank-skewed)
  __shared__ unsigned hist[4][256];
  __shared__ u64 bk[4][32];
  __shared__ int bcnt[4], bbin[4], bneed[4];
  __shared__ unsigned char sf[4][512];
  __shared__ float wred[4][2];
  __shared__ int slast;

  const int tid = threadIdx.x;
  const int lane = tid & 63, wv = tid >> 6;
  const int bid = blockIdx.x;
  const int b = bid >> 5, m0 = (bid & 31) * 16;
  const int r16 = lane & 15, g = lane >> 4;

  //---- Phase A: GEMM strip (16 x 512), bf16 MFMA, no LDS staging ----
  {
    const u16* Arow = MC + ((size_t)(b * NM + m0 + r16)) * NC + g * 8;
    bf16x8 a[8];
#pragma unroll
    for (int ks = 0; ks < 8; ++ks) a[ks] = *(const bf16x8*)(Arow + ks * 32);

    const u16* Bbase = MF + ((size_t)(b * NM + wv * 128 + r16)) * NC + g * 8;
    f32x4 zero = {0.f, 0.f, 0.f, 0.f};
    f32x4 acc[8];
#pragma unroll
    for (int n = 0; n < 8; ++n) acc[n] = zero;

#pragma unroll
    for (int ks = 0; ks < 8; ++ks) {
#pragma unroll
      for (int n = 0; n < 8; ++n) {
        bf16x8 bv = *(const bf16x8*)(Bbase + (size_t)n * 16 * NC + ks * 32);
        acc[n] = __builtin_amdgcn_mfma_f32_16x16x32_bf16(a[ks], bv, acc[n], 0, 0, 0);
      }
    }

#pragma unroll
    for (int n = 0; n < 8; ++n)
#pragma unroll
      for (int q = 0; q < 4; ++q)
        S_lds[g * 4 + q][wv * 128 + n * 16 + r16] = acc[n][q];
  }
  __syncthreads();

  //---- Phase B: per-wave selection + softmax, 4 rows per wave (R8-proven) ---
  float wsum_pl = 0.f, wsum_pa = 0.f;
  for (int rr = 0; rr < 4; ++rr) {
    const int rloc = wv * 4 + rr;
    const int m = m0 + rloc;               // self index within batch row
    const int row = b * NM + m;            // global row (threefry stream)

#pragma unroll
    for (int q = 0; q < 4; ++q) hist[wv][lane * 4 + q] = 0;
#pragma unroll
    for (int j = 0; j < 8; ++j) sf[wv][j * 64 + lane] = 0;
    if (lane == 0) bcnt[wv] = 0;

    unsigned keys[8]; int bins[8]; bool selfj[8];
#pragma unroll
    for (int j = 0; j < 8; ++j) {
      int t = j * 64 + lane;
      unsigned bits = threefry_bits((unsigned)row * 512u + (unsigned)t);
      unsigned u = bits >> 9;
      keys[j] = (u << 9) | (unsigned)(511 - t);
      bins[j] = (int)(u >> 15);
      selfj[j] = (t == m);
      if (!selfj[j]) atomicAdd(&hist[wv][bins[j]], 1u);
    }
    WAVE_LDS_FENCE();  // F1: hist atomics -> scan reads

    {
      unsigned h0 = hist[wv][4 * lane + 0], h1 = hist[wv][4 * lane + 1];
      unsigned h2 = hist[wv][4 * lane + 2], h3 = hist[wv][4 * lane + 3];
      unsigned s = h0 + h1 + h2 + h3;
      unsigned suf = s;
#pragma unroll
      for (int off = 1; off < 64; off <<= 1) {
        unsigned o = __shfl_down(suf, off, 64);
        if (lane + off < 64) suf += o;
      }
      unsigned a3 = suf - s;
      unsigned a2 = a3 + h3;
      unsigned a1 = a2 + h2;
      unsigned a0 = a1 + h1;
      if (a3 < NNEG && a3 + h3 >= NNEG) { bbin[wv] = 4 * lane + 3; bneed[wv] = NNEG - (int)a3; }
      if (a2 < NNEG && a2 + h2 >= NNEG) { bbin[wv] = 4 * lane + 2; bneed[wv] = NNEG - (int)a2; }
      if (a1 < NNEG && a1 + h1 >= NNEG) { bbin[wv] = 4 * lane + 1; bneed[wv] = NNEG - (int)a1; }
      if (a0 < NNEG && a0 + h0 >= NNEG) { bbin[wv] = 4 * lane + 0; bneed[wv] = NNEG - (int)a0; }
    }
    WAVE_LDS_FENCE();  // F2: bbin/bneed -> all lanes

    const int bb = bbin[wv];
#pragma unroll
    for (int j = 0; j < 8; ++j) {
      if (!selfj[j] && bins[j] == bb) {
        int p = atomicAdd(&bcnt[wv], 1);
        bk[wv][p & 31] = (((u64)keys[j]) << 1) | 1ull;
      }
    }
    WAVE_LDS_FENCE();  // F3: bk/bcnt -> lane 0

    if (lane == 0) {
      int cnt = bcnt[wv]; if (cnt > 32) cnt = 32;
      int need = bneed[wv];
      for (int it = 0; it < need; ++it) {
        u64 best = 0ull; int bi = 0;
        for (int q = 0; q < cnt; ++q)
          if (bk[wv][q] > best) { best = bk[wv][q]; bi = q; }
        bk[wv][bi] = 0ull;
        int tt = 511 - (int)((best >> 1) & 511ull);
        sf[wv][tt] = 1;
      }
    }
    WAVE_LDS_FENCE();  // F4: lane 0's sf -> all lanes

    float lv[8]; bool act[8];
    float mv = -3.4e38f;
#pragma unroll
    for (int j = 0; j < 8; ++j) {
      lv[j] = S_lds[rloc][j * 64 + lane];
      act[j] = selfj[j] || (bins[j] > bb && !selfj[j]) || (sf[wv][j * 64 + lane] != 0);
      if (act[j]) mv = fmaxf(mv, lv[j]);
    }
#pragma unroll
    for (int off = 32; off > 0; off >>= 1) mv = fmaxf(mv, __shfl_xor(mv, off, 64));

    float es = 0.f, as = 0.f, ps = 0.f;
#pragma unroll
    for (int j = 0; j < 8; ++j) {
      if (act[j]) {
        float e = __expf(lv[j] - mv);
        float th = 1.f - 2.f / (__expf(2.f * lv[j]) + 1.f);
        es += e; as += th * th;
        if (selfj[j]) ps = e;
      }
    }
#pragma unroll
    for (int off = 32; off > 0; off >>= 1) {
      es += __shfl_xor(es, off, 64);
      as += __shfl_xor(as, off, 64);
      ps += __shfl_xor(ps, off, 64);
    }
    if (lane == 0) { wsum_pl += ps / es; wsum_pa += as; }
    WAVE_LDS_FENCE();  // WAR: sf/hist reads complete before next-iter zeroing
  }

  if (lane == 0) { wred[wv][0] = wsum_pl; wred[wv][1] = wsum_pa; }
  __syncthreads();

  //---- Phase C: block partial + last-block fixed-order reduction ----
  if (tid == 0) {
    float bpl = wred[0][0] + wred[1][0] + wred[2][0] + wred[3][0];
    float bpa = wred[0][1] + wred[1][1] + wred[2][1] + wred[3][1];
    partials[2 * bid] = bpl;
    partials[2 * bid + 1] = bpa;
    __threadfence();
    int old = atomicAdd(counter, 1);
    slast = (old == 255);
  }
  __syncthreads();
  if (slast) {
    __threadfence();
    float* s1 = (float*)hist;   // reuse LDS
    float* s2 = s1 + 256;
    s1[tid] = partials[2 * tid];
    s2[tid] = partials[2 * tid + 1];
    __syncthreads();
    for (int off = 128; off > 0; off >>= 1) {
      if (tid < off) { s1[tid] += s1[tid + off]; s2[tid] += s2[tid + off]; }
      __syncthreads();
    }
    if (tid == 0) { out[0] = s1[0]; out[1] = s2[0]; }
  }
}

extern "C" void kernel_launch(void* const* d_in, const int* in_sizes, int n_in,
                              void* d_out, int out_size, void* d_ws, size_t ws_size,
                              hipStream_t stream) {
  const float* feat = (const float*)d_in[0];  // feat_proj [B,C,T]
  const void*  mask = d_in[1];                // mask [B,T] bool
  const float* ctx  = (const float*)d_in[2];  // context_output [B,C,T]
  float* out = (float*)d_out;

  char* ws = (char*)d_ws;
  u16*   MC      = (u16*)ws;                       // 2 MB [B,M,C] bf16 (ctx)
  u16*   MF      = (u16*)(ws + (2u << 20));        // 2 MB [B,M,C] bf16 (feat)
  float* partials = (float*)(ws + (4u << 20));     // 256*2 f32
  int*   counter  = (int*)(ws + (4u << 20) + 4096);

  dim3 gc(NT / 128, NB * 2);
  k_compact<<<gc, 256, 0, stream>>>(ctx, feat, mask, MC, MF, counter);

  k_fused<<<NB * 32, 256, 0, stream>>>(MC, MF, partials, counter, out);
}

// Round 10
// 54.925 us; speedup vs baseline: 1.0803x; 1.0803x over previous
//
#include <hip/hip_runtime.h>
#include <stdint.h>

#define NB   8
#define NC   256
#define NT   1024
#define NM   512
#define NNEG 100

typedef unsigned short u16;
typedef unsigned long long u64;
typedef __attribute__((ext_vector_type(8))) short bf16x8;
typedef __attribute__((ext_vector_type(4))) float f32x4;

// wave-level LDS visibility fence (proven R8)
#define WAVE_LDS_FENCE() asm volatile("s_waitcnt lgkmcnt(0)" ::: "memory")

// ---------------- Threefry-2x32-20 (JAX) ----------------
__device__ __forceinline__ unsigned rotl32(unsigned x, int d) {
  return (x << d) | (x >> (32 - d));
}

__device__ unsigned threefry_bits(unsigned i) {
  const unsigned half = 1048576u; // 2^20
  const bool lo = i < half;
  unsigned v0 = lo ? i : (i - half);
  unsigned v1 = lo ? (i + half) : i;
  const unsigned k0 = 0u, k1 = 42u;
  const unsigned k2 = k0 ^ k1 ^ 0x1BD11BDAu;
  v0 += k0; v1 += k1;
#define TF_R(r) { v0 += v1; v1 = rotl32(v1, r); v1 ^= v0; }
  TF_R(13) TF_R(15) TF_R(26) TF_R(6)
  v0 += k1; v1 += k2 + 1u;
  TF_R(17) TF_R(29) TF_R(16) TF_R(24)
  v0 += k2; v1 += k0 + 2u;
  TF_R(13) TF_R(15) TF_R(26) TF_R(6)
  v0 += k0; v1 += k1 + 3u;
  TF_R(17) TF_R(29) TF_R(16) TF_R(24)
  v0 += k1; v1 += k2 + 4u;
  TF_R(13) TF_R(15) TF_R(26) TF_R(6)
  v0 += k2; v1 += k0 + 5u;
#undef TF_R
  return lo ? v0 : v1;
}

// ---------------- Kernel 1: compact + bf16 RTN (R9-validated) ----------------
__global__ __launch_bounds__(256) void k_compact(const float* __restrict__ ctx,
                                                 const float* __restrict__ feat,
                                                 const void* __restrict__ maskp,
                                                 u16* __restrict__ MC, u16* __restrict__ MF,
                                                 int* __restrict__ counter) {
  __shared__ float lds[64][129];
  __shared__ int posl[128];
  __shared__ int wsum[4];
  __shared__ int det[3];
  const int tid = threadIdx.x;
  const int lane = tid & 63, wid = tid >> 6;
  const int t0 = blockIdx.x * 128;
  const int b = blockIdx.y >> 1, mat = blockIdx.y & 1;
  const unsigned char* mb = (const unsigned char*)maskp;

  if (blockIdx.x == 0 && blockIdx.y == 0 && tid == 0) *counter = 0;

  if (tid < 3) det[tid] = 0;
  __syncthreads();
  {
    int c1 = 0, c4 = 0, c8 = 0;
    for (int j = tid; j < 1024; j += 256) {
      c1 += (mb[j] != 0);
      c4 += (((const unsigned*)mb)[j] != 0u);
      c8 += (((const u64*)mb)[j] != 0ull);
    }
#pragma unroll
    for (int off = 32; off; off >>= 1) {
      c1 += __shfl_xor(c1, off, 64);
      c4 += __shfl_xor(c4, off, 64);
      c8 += __shfl_xor(c8, off, 64);
    }
    if (lane == 0) { atomicAdd(&det[0], c1); atomicAdd(&det[1], c4); atomicAdd(&det[2], c8); }
  }
  __syncthreads();
  const int stride = (det[1] == 512) ? 4 : ((det[0] == 512) ? 1 : ((det[2] == 512) ? 8 : 4));

  int f4[4]; int s = 0;
#pragma unroll
  for (int j = 0; j < 4; ++j) {
    int tt = 4 * tid + j;
    size_t e = (size_t)b * NT + tt;
    int f;
    if (stride == 1)      f = (mb[e] != 0);
    else if (stride == 4) f = (((const unsigned*)mb)[e] != 0u);
    else                  f = (((const u64*)mb)[e] != 0ull);
    f4[j] = f; s += f;
  }
  int incl = s;
#pragma unroll
  for (int off = 1; off < 64; off <<= 1) {
    int o = __shfl_up(incl, off, 64);
    if (lane >= off) incl += o;
  }
  if (lane == 63) wsum[wid] = incl;
  __syncthreads();
  int wbase = 0;
#pragma unroll
  for (int w = 0; w < 4; ++w) if (w < wid) wbase += wsum[w];
  int excl = wbase + incl - s;
#pragma unroll
  for (int j = 0; j < 4; ++j) {
    int tt = 4 * tid + j;
    if (tt >= t0 && tt < t0 + 128) posl[tt - t0] = f4[j] ? excl : -1;
    excl += f4[j];
  }

  const float* src = (mat ? feat : ctx) + (size_t)b * NC * NT;
  u16* dst = (mat ? MF : MC) + (size_t)b * NM * NC;

  const int c4i = tid >> 6, tl = tid & 63, tr = tid >> 6;
  for (int chunk = 0; chunk < 4; ++chunk) {
    int c0 = chunk * 64;
    __syncthreads();
    for (int ci = 0; ci < 16; ++ci) {
      int cc = c4i * 16 + ci;
#pragma unroll
      for (int tj = 0; tj < 2; ++tj) {
        int tt = tl + 64 * tj;
        lds[cc][tt] = src[(size_t)(c0 + cc) * NT + t0 + tt];
      }
    }
    __syncthreads();
    for (int tt = tr; tt < 128; tt += 4) {
      int p = posl[tt];
      if (p >= 0) {
        unsigned xb = __float_as_uint(lds[tl][tt]);
        xb += 0x7FFFu + ((xb >> 16) & 1u);   // round-to-nearest-even bf16
        dst[(size_t)p * NC + c0 + tl] = (u16)(xb >> 16);
      }
    }
  }
}

// ---------------- Kernel 2: bf16 MFMA GEMM, 64x64 tile, single plane --------
// 4 waves (2x2), wave = 32x32 quadrant = 2x2 frags, 1 MFMA per frag per ks.
__global__ __launch_bounds__(256) void k_gemm(const u16* __restrict__ MC,
                                              const u16* __restrict__ MF,
                                              float* __restrict__ S) {
  __shared__ u16 smem[2][5120]; // per buf: A[64][40] @0, B[64][40] @2560
  const int tid = threadIdx.x;
  const int b = blockIdx.z, m0 = blockIdx.y * 64, j0 = blockIdx.x * 64;
  const int wave = tid >> 6, lane = tid & 63;
  const int wm = wave >> 1, wn = wave & 1;
  const int r = lane & 15, g = lane >> 4;

  // staging: thread -> (row 0..63, q 0..3): one uint4 from A and one from B
  const int srow = tid >> 2, sq = tid & 3;
  const u16* Asrc = MC + (size_t)(b * NM + m0 + srow) * NC + sq * 8;
  const u16* Bsrc = MF + (size_t)(b * NM + j0 + srow) * NC + sq * 8;
  const int sdst = srow * 40 + sq * 8;

  uint4 ra, rb;
  auto load_regs = [&](int c0) {
    ra = *(const uint4*)(Asrc + c0);
    rb = *(const uint4*)(Bsrc + c0);
  };
  auto write_lds = [&](int buf) {
    *(uint4*)(smem[buf] + sdst) = ra;
    *(uint4*)(smem[buf] + 2560 + sdst) = rb;
  };

  f32x4 zero = {0.f, 0.f, 0.f, 0.f};
  f32x4 acc[2][2];
#pragma unroll
  for (int m = 0; m < 2; ++m)
#pragma unroll
    for (int n = 0; n < 2; ++n) acc[m][n] = zero;

  load_regs(0);
  write_lds(0);
  __syncthreads();

  for (int ks = 0; ks < 8; ++ks) {
    const int cur = ks & 1;
    if (ks < 7) load_regs((ks + 1) * 32);
    const u16* base = smem[cur];
    bf16x8 a[2], bvv[2];
#pragma unroll
    for (int m = 0; m < 2; ++m)
      a[m] = *(const bf16x8*)(base + (wm * 32 + m * 16 + r) * 40 + g * 8);
#pragma unroll
    for (int n = 0; n < 2; ++n)
      bvv[n] = *(const bf16x8*)(base + 2560 + (wn * 32 + n * 16 + r) * 40 + g * 8);
#pragma unroll
    for (int m = 0; m < 2; ++m)
#pragma unroll
      for (int n = 0; n < 2; ++n)
        acc[m][n] = __builtin_amdgcn_mfma_f32_16x16x32_bf16(a[m], bvv[n], acc[m][n], 0, 0, 0);
    if (ks < 7) write_lds(cur ^ 1);
    __syncthreads();
  }

  float* Sb = S + (size_t)b * NM * NM;
#pragma unroll
  for (int m = 0; m < 2; ++m)
#pragma unroll
    for (int n = 0; n < 2; ++n)
#pragma unroll
      for (int q = 0; q < 4; ++q) {
        int rowi = m0 + wm * 32 + m * 16 + g * 4 + q;
        int col  = j0 + wn * 32 + n * 16 + r;
        Sb[(size_t)rowi * NM + col] = acc[m][n][q];
      }
}

// ---------------- Kernel 3: wave-per-row top-100 + loss + final reduce ------
// 8 waves/block (R8-proven fenced body) + last-block fixed-order reduction.
__global__ __launch_bounds__(512) void k_loss(const float* __restrict__ S,
                                              float* __restrict__ partials,
                                              int* __restrict__ counter,
                                              float* __restrict__ out) {
  __shared__ unsigned hist[8][256];
  __shared__ u64 bk[8][32];
  __shared__ int bcnt[8], bbin[8], bneed[8];
  __shared__ unsigned char sf[8][512];
  __shared__ float wred[8][2];
  __shared__ int slast;

  const int tid = threadIdx.x;
  const int lane = tid & 63, wv = tid >> 6;
  const int row = blockIdx.x * 8 + wv;
  const int m = row & (NM - 1);

#pragma unroll
  for (int q = 0; q < 4; ++q) hist[wv][lane * 4 + q] = 0;
#pragma unroll
  for (int j = 0; j < 8; ++j) sf[wv][j * 64 + lane] = 0;
  if (lane == 0) bcnt[wv] = 0;

  unsigned keys[8]; int bins[8]; bool selfj[8];
#pragma unroll
  for (int j = 0; j < 8; ++j) {
    int t = j * 64 + lane;
    unsigned bits = threefry_bits((unsigned)row * 512u + (unsigned)t);
    unsigned u = bits >> 9;
    keys[j] = (u << 9) | (unsigned)(511 - t);
    bins[j] = (int)(u >> 15);
    selfj[j] = (t == m);
    if (!selfj[j]) atomicAdd(&hist[wv][bins[j]], 1u);
  }
  WAVE_LDS_FENCE();  // F1

  {
    unsigned h0 = hist[wv][4 * lane + 0], h1 = hist[wv][4 * lane + 1];
    unsigned h2 = hist[wv][4 * lane + 2], h3 = hist[wv][4 * lane + 3];
    unsigned s = h0 + h1 + h2 + h3;
    unsigned suf = s;
#pragma unroll
    for (int off = 1; off < 64; off <<= 1) {
      unsigned o = __shfl_down(suf, off, 64);
      if (lane + off < 64) suf += o;
    }
    unsigned a3 = suf - s;
    unsigned a2 = a3 + h3;
    unsigned a1 = a2 + h2;
    unsigned a0 = a1 + h1;
    if (a3 < NNEG && a3 + h3 >= NNEG) { bbin[wv] = 4 * lane + 3; bneed[wv] = NNEG - (int)a3; }
    if (a2 < NNEG && a2 + h2 >= NNEG) { bbin[wv] = 4 * lane + 2; bneed[wv] = NNEG - (int)a2; }
    if (a1 < NNEG && a1 + h1 >= NNEG) { bbin[wv] = 4 * lane + 1; bneed[wv] = NNEG - (int)a1; }
    if (a0 < NNEG && a0 + h0 >= NNEG) { bbin[wv] = 4 * lane + 0; bneed[wv] = NNEG - (int)a0; }
  }
  WAVE_LDS_FENCE();  // F2

  const int bb = bbin[wv];
#pragma unroll
  for (int j = 0; j < 8; ++j) {
    if (!selfj[j] && bins[j] == bb) {
      int p = atomicAdd(&bcnt[wv], 1);
      bk[wv][p & 31] = (((u64)keys[j]) << 1) | 1ull;
    }
  }
  WAVE_LDS_FENCE();  // F3

  if (lane == 0) {
    int cnt = bcnt[wv]; if (cnt > 32) cnt = 32;
    int need = bneed[wv];
    for (int it = 0; it < need; ++it) {
      u64 best = 0ull; int bi = 0;
      for (int q = 0; q < cnt; ++q)
        if (bk[wv][q] > best) { best = bk[wv][q]; bi = q; }
      bk[wv][bi] = 0ull;
      int tt = 511 - (int)((best >> 1) & 511ull);
      sf[wv][tt] = 1;
    }
  }
  WAVE_LDS_FENCE();  // F4

  const float* Srow = S + (size_t)row * NM;
  float lv[8]; bool act[8];
  float mv = -3.4e38f;
#pragma unroll
  for (int j = 0; j < 8; ++j) {
    lv[j] = Srow[j * 64 + lane];
    act[j] = selfj[j] || (bins[j] > bb && !selfj[j]) || (sf[wv][j * 64 + lane] != 0);
    if (act[j]) mv = fmaxf(mv, lv[j]);
  }
#pragma unroll
  for (int off = 32; off > 0; off >>= 1) mv = fmaxf(mv, __shfl_xor(mv, off, 64));

  float es = 0.f, as = 0.f, ps = 0.f;
#pragma unroll
  for (int j = 0; j < 8; ++j) {
    if (act[j]) {
      float e = __expf(lv[j] - mv);
      float th = 1.f - 2.f / (__expf(2.f * lv[j]) + 1.f);
      es += e; as += th * th;
      if (selfj[j]) ps = e;
    }
  }
#pragma unroll
  for (int off = 32; off > 0; off >>= 1) {
    es += __shfl_xor(es, off, 64);
    as += __shfl_xor(as, off, 64);
    ps += __shfl_xor(ps, off, 64);
  }
  if (lane == 0) { wred[wv][0] = ps / es; wred[wv][1] = as; }
  __syncthreads();

  // block partial + last-block deterministic reduce (R9-proven pattern)
  if (tid == 0) {
    float bpl = 0.f, bpa = 0.f;
#pragma unroll
    for (int w = 0; w < 8; ++w) { bpl += wred[w][0]; bpa += wred[w][1]; }
    partials[2 * blockIdx.x] = bpl;
    partials[2 * blockIdx.x + 1] = bpa;
    __threadfence();
    int old = atomicAdd(counter, 1);
    slast = (old == 511);
  }
  __syncthreads();
  if (slast) {
    __threadfence();
    float* s1 = (float*)hist;   // reuse LDS (8KB >= 4KB)
    float* s2 = s1 + 512;
    s1[tid] = partials[2 * tid];
    s2[tid] = partials[2 * tid + 1];
    __syncthreads();
    for (int off = 256; off > 0; off >>= 1) {
      if (tid < off) { s1[tid] += s1[tid + off]; s2[tid] += s2[tid + off]; }
      __syncthreads();
    }
    if (tid == 0) { out[0] = s1[0]; out[1] = s2[0]; }
  }
}

extern "C" void kernel_launch(void* const* d_in, const int* in_sizes, int n_in,
                              void* d_out, int out_size, void* d_ws, size_t ws_size,
                              hipStream_t stream) {
  const float* feat = (const float*)d_in[0];  // feat_proj [B,C,T]
  const void*  mask = d_in[1];                // mask [B,T] bool
  const float* ctx  = (const float*)d_in[2];  // context_output [B,C,T]
  float* out = (float*)d_out;

  char* ws = (char*)d_ws;
  u16*   MC       = (u16*)ws;                      // 2 MB [B,M,C] bf16 (ctx)
  u16*   MF       = (u16*)(ws + (2u << 20));       // 2 MB [B,M,C] bf16 (feat)
  float* S        = (float*)(ws + (4u << 20));     // 8 MB [B,M,M] f32
  float* partials = (float*)(ws + (12u << 20));    // 512*2 f32
  int*   counter  = (int*)(ws + (12u << 20) + 8192);

  dim3 gc(NT / 128, NB * 2);
  k_compact<<<gc, 256, 0, stream>>>(ctx, feat, mask, MC, MF, counter);

  dim3 g2(NM / 64, NM / 64, NB);  // 512 blocks
  k_gemm<<<g2, 256, 0, stream>>>(MC, MF, S);

  k_loss<<<NB * NM / 8, 512, 0, stream>>>(S, partials, counter, out);
}

// Round 11
// 53.803 us; speedup vs baseline: 1.1028x; 1.0209x over previous
//
#include <hip/hip_runtime.h>
#include <stdint.h>

#define NB   8
#define NC   256
#define NT   1024
#define NM   512
#define NNEG 100

typedef unsigned short u16;
typedef unsigned long long u64;
typedef __attribute__((ext_vector_type(8))) short bf16x8;
typedef __attribute__((ext_vector_type(4))) float f32x4;

// wave-level LDS visibility fence (proven R8)
#define WAVE_LDS_FENCE() asm volatile("s_waitcnt lgkmcnt(0)" ::: "memory")

// ---------------- Threefry-2x32-20 (JAX) ----------------
__device__ __forceinline__ unsigned rotl32(unsigned x, int d) {
  return (x << d) | (x >> (32 - d));
}

__device__ unsigned threefry_bits(unsigned i) {
  const unsigned half = 1048576u; // 2^20
  const bool lo = i < half;
  unsigned v0 = lo ? i : (i - half);
  unsigned v1 = lo ? (i + half) : i;
  const unsigned k0 = 0u, k1 = 42u;
  const unsigned k2 = k0 ^ k1 ^ 0x1BD11BDAu;
  v0 += k0; v1 += k1;
#define TF_R(r) { v0 += v1; v1 = rotl32(v1, r); v1 ^= v0; }
  TF_R(13) TF_R(15) TF_R(26) TF_R(6)
  v0 += k1; v1 += k2 + 1u;
  TF_R(17) TF_R(29) TF_R(16) TF_R(24)
  v0 += k2; v1 += k0 + 2u;
  TF_R(13) TF_R(15) TF_R(26) TF_R(6)
  v0 += k0; v1 += k1 + 3u;
  TF_R(17) TF_R(29) TF_R(16) TF_R(24)
  v0 += k1; v1 += k2 + 4u;
  TF_R(13) TF_R(15) TF_R(26) TF_R(6)
  v0 += k2; v1 += k0 + 5u;
#undef TF_R
  return lo ? v0 : v1;
}

// ---------------- Kernel 1: compact + bf16 RTN (R10 verbatim) ----------------
__global__ __launch_bounds__(256) void k_compact(const float* __restrict__ ctx,
                                                 const float* __restrict__ feat,
                                                 const void* __restrict__ maskp,
                                                 u16* __restrict__ MC, u16* __restrict__ MF,
                                                 int* __restrict__ counter) {
  __shared__ float lds[64][129];
  __shared__ int posl[128];
  __shared__ int wsum[4];
  __shared__ int det[3];
  const int tid = threadIdx.x;
  const int lane = tid & 63, wid = tid >> 6;
  const int t0 = blockIdx.x * 128;
  const int b = blockIdx.y >> 1, mat = blockIdx.y & 1;
  const unsigned char* mb = (const unsigned char*)maskp;

  if (blockIdx.x == 0 && blockIdx.y == 0 && tid == 0) *counter = 0;

  if (tid < 3) det[tid] = 0;
  __syncthreads();
  {
    int c1 = 0, c4 = 0, c8 = 0;
    for (int j = tid; j < 1024; j += 256) {
      c1 += (mb[j] != 0);
      c4 += (((const unsigned*)mb)[j] != 0u);
      c8 += (((const u64*)mb)[j] != 0ull);
    }
#pragma unroll
    for (int off = 32; off; off >>= 1) {
      c1 += __shfl_xor(c1, off, 64);
      c4 += __shfl_xor(c4, off, 64);
      c8 += __shfl_xor(c8, off, 64);
    }
    if (lane == 0) { atomicAdd(&det[0], c1); atomicAdd(&det[1], c4); atomicAdd(&det[2], c8); }
  }
  __syncthreads();
  const int stride = (det[1] == 512) ? 4 : ((det[0] == 512) ? 1 : ((det[2] == 512) ? 8 : 4));

  int f4[4]; int s = 0;
#pragma unroll
  for (int j = 0; j < 4; ++j) {
    int tt = 4 * tid + j;
    size_t e = (size_t)b * NT + tt;
    int f;
    if (stride == 1)      f = (mb[e] != 0);
    else if (stride == 4) f = (((const unsigned*)mb)[e] != 0u);
    else                  f = (((const u64*)mb)[e] != 0ull);
    f4[j] = f; s += f;
  }
  int incl = s;
#pragma unroll
  for (int off = 1; off < 64; off <<= 1) {
    int o = __shfl_up(incl, off, 64);
    if (lane >= off) incl += o;
  }
  if (lane == 63) wsum[wid] = incl;
  __syncthreads();
  int wbase = 0;
#pragma unroll
  for (int w = 0; w < 4; ++w) if (w < wid) wbase += wsum[w];
  int excl = wbase + incl - s;
#pragma unroll
  for (int j = 0; j < 4; ++j) {
    int tt = 4 * tid + j;
    if (tt >= t0 && tt < t0 + 128) posl[tt - t0] = f4[j] ? excl : -1;
    excl += f4[j];
  }

  const float* src = (mat ? feat : ctx) + (size_t)b * NC * NT;
  u16* dst = (mat ? MF : MC) + (size_t)b * NM * NC;

  const int c4i = tid >> 6, tl = tid & 63, tr = tid >> 6;
  for (int chunk = 0; chunk < 4; ++chunk) {
    int c0 = chunk * 64;
    __syncthreads();
    for (int ci = 0; ci < 16; ++ci) {
      int cc = c4i * 16 + ci;
#pragma unroll
      for (int tj = 0; tj < 2; ++tj) {
        int tt = tl + 64 * tj;
        lds[cc][tt] = src[(size_t)(c0 + cc) * NT + t0 + tt];
      }
    }
    __syncthreads();
    for (int tt = tr; tt < 128; tt += 4) {
      int p = posl[tt];
      if (p >= 0) {
        unsigned xb = __float_as_uint(lds[tl][tt]);
        xb += 0x7FFFu + ((xb >> 16) & 1u);   // round-to-nearest-even bf16
        dst[(size_t)p * NC + c0 + tl] = (u16)(xb >> 16);
      }
    }
  }
}

// ---------------- Kernel 2: fused strip-GEMM + selection + loss + reduce ----
// 256 blocks x 512 thr (8 waves = 2/SIMD; R9 retry at 2x occupancy).
// Strip = 16 rows x all 512 cols of S, held in LDS (kills the 16 MB S
// round-trip). Phase B = R8/R10-proven fenced wave body, 2 rows/wave.
__global__ __launch_bounds__(512) void k_fused(const u16* __restrict__ MC,
                                               const u16* __restrict__ MF,
                                               float* __restrict__ partials,
                                               int* __restrict__ counter,
                                               float* __restrict__ out) {
  __shared__ float S_lds[16][516];            // 33 KB, pitch 516
  __shared__ unsigned hist[8][256];           // 8 KB
  __shared__ u64 bk[8][32];                   // 2 KB
  __shared__ int bcnt[8], bbin[8], bneed[8];
  __shared__ unsigned char sf[8][512];        // 4 KB
  __shared__ float wred[8][2];
  __shared__ int slast;

  const int tid = threadIdx.x;
  const int lane = tid & 63, wv = tid >> 6;
  const int bid = blockIdx.x;
  const int b = bid >> 5, m0 = (bid & 31) * 16;
  const int r16 = lane & 15, g = lane >> 4;

  //---- Phase A: strip GEMM (16 x 512), B streamed from L2 (R9-validated) ----
  {
    const u16* Arow = MC + ((size_t)(b * NM + m0 + r16)) * NC + g * 8;
    bf16x8 a[8];
#pragma unroll
    for (int ks = 0; ks < 8; ++ks) a[ks] = *(const bf16x8*)(Arow + ks * 32);

    const u16* Bbase = MF + ((size_t)(b * NM + wv * 64 + r16)) * NC + g * 8;
    f32x4 zero = {0.f, 0.f, 0.f, 0.f};
    f32x4 acc[4];
#pragma unroll
    for (int n = 0; n < 4; ++n) acc[n] = zero;

#pragma unroll
    for (int ks = 0; ks < 8; ++ks) {
#pragma unroll
      for (int n = 0; n < 4; ++n) {
        bf16x8 bv = *(const bf16x8*)(Bbase + (size_t)n * 16 * NC + ks * 32);
        acc[n] = __builtin_amdgcn_mfma_f32_16x16x32_bf16(a[ks], bv, acc[n], 0, 0, 0);
      }
    }

#pragma unroll
    for (int n = 0; n < 4; ++n)
#pragma unroll
      for (int q = 0; q < 4; ++q)
        S_lds[g * 4 + q][wv * 64 + n * 16 + r16] = acc[n][q];
  }
  __syncthreads();

  //---- Phase B: fenced wave selection + softmax, 2 rows/wave (R8-proven) ----
  float wsum_pl = 0.f, wsum_pa = 0.f;
  for (int rr = 0; rr < 2; ++rr) {
    const int rloc = wv * 2 + rr;
    const int m = m0 + rloc;
    const int row = b * NM + m;

#pragma unroll
    for (int q = 0; q < 4; ++q) hist[wv][lane * 4 + q] = 0;
#pragma unroll
    for (int j = 0; j < 8; ++j) sf[wv][j * 64 + lane] = 0;
    if (lane == 0) bcnt[wv] = 0;
    WAVE_LDS_FENCE();  // zeroing visible before atomics

    unsigned keys[8]; int bins[8]; bool selfj[8];
#pragma unroll
    for (int j = 0; j < 8; ++j) {
      int t = j * 64 + lane;
      unsigned bits = threefry_bits((unsigned)row * 512u + (unsigned)t);
      unsigned u = bits >> 9;
      keys[j] = (u << 9) | (unsigned)(511 - t);
      bins[j] = (int)(u >> 15);
      selfj[j] = (t == m);
      if (!selfj[j]) atomicAdd(&hist[wv][bins[j]], 1u);
    }
    WAVE_LDS_FENCE();  // F1

    {
      unsigned h0 = hist[wv][4 * lane + 0], h1 = hist[wv][4 * lane + 1];
      unsigned h2 = hist[wv][4 * lane + 2], h3 = hist[wv][4 * lane + 3];
      unsigned s = h0 + h1 + h2 + h3;
      unsigned suf = s;
#pragma unroll
      for (int off = 1; off < 64; off <<= 1) {
        unsigned o = __shfl_down(suf, off, 64);
        if (lane + off < 64) suf += o;
      }
      unsigned a3 = suf - s;
      unsigned a2 = a3 + h3;
      unsigned a1 = a2 + h2;
      unsigned a0 = a1 + h1;
      if (a3 < NNEG && a3 + h3 >= NNEG) { bbin[wv] = 4 * lane + 3; bneed[wv] = NNEG - (int)a3; }
      if (a2 < NNEG && a2 + h2 >= NNEG) { bbin[wv] = 4 * lane + 2; bneed[wv] = NNEG - (int)a2; }
      if (a1 < NNEG && a1 + h1 >= NNEG) { bbin[wv] = 4 * lane + 1; bneed[wv] = NNEG - (int)a1; }
      if (a0 < NNEG && a0 + h0 >= NNEG) { bbin[wv] = 4 * lane + 0; bneed[wv] = NNEG - (int)a0; }
    }
    WAVE_LDS_FENCE();  // F2

    const int bb = bbin[wv];
#pragma unroll
    for (int j = 0; j < 8; ++j) {
      if (!selfj[j] && bins[j] == bb) {
        int p = atomicAdd(&bcnt[wv], 1);
        bk[wv][p & 31] = (((u64)keys[j]) << 1) | 1ull;
      }
    }
    WAVE_LDS_FENCE();  // F3

    if (lane == 0) {
      int cnt = bcnt[wv]; if (cnt > 32) cnt = 32;
      int need = bneed[wv];
      for (int it = 0; it < need; ++it) {
        u64 best = 0ull; int bi = 0;
        for (int q = 0; q < cnt; ++q)
          if (bk[wv][q] > best) { best = bk[wv][q]; bi = q; }
        bk[wv][bi] = 0ull;
        int tt = 511 - (int)((best >> 1) & 511ull);
        sf[wv][tt] = 1;
      }
    }
    WAVE_LDS_FENCE();  // F4

    float lv[8]; bool act[8];
    float mv = -3.4e38f;
#pragma unroll
    for (int j = 0; j < 8; ++j) {
      lv[j] = S_lds[rloc][j * 64 + lane];
      act[j] = selfj[j] || (bins[j] > bb && !selfj[j]) || (sf[wv][j * 64 + lane] != 0);
      if (act[j]) mv = fmaxf(mv, lv[j]);
    }
#pragma unroll
    for (int off = 32; off > 0; off >>= 1) mv = fmaxf(mv, __shfl_xor(mv, off, 64));

    float es = 0.f, as = 0.f, ps = 0.f;
#pragma unroll
    for (int j = 0; j < 8; ++j) {
      if (act[j]) {
        float e = __expf(lv[j] - mv);
        float th = 1.f - 2.f / (__expf(2.f * lv[j]) + 1.f);
        es += e; as += th * th;
        if (selfj[j]) ps = e;
      }
    }
#pragma unroll
    for (int off = 32; off > 0; off >>= 1) {
      es += __shfl_xor(es, off, 64);
      as += __shfl_xor(as, off, 64);
      ps += __shfl_xor(ps, off, 64);
    }
    if (lane == 0) { wsum_pl += ps / es; wsum_pa += as; }
    WAVE_LDS_FENCE();  // WAR before next-iter zeroing
  }

  if (lane == 0) { wred[wv][0] = wsum_pl; wred[wv][1] = wsum_pa; }
  __syncthreads();

  //---- Phase C: block partial + last-block fixed-order reduce (proven) ------
  if (tid == 0) {
    float bpl = 0.f, bpa = 0.f;
#pragma unroll
    for (int w = 0; w < 8; ++w) { bpl += wred[w][0]; bpa += wred[w][1]; }
    partials[2 * bid] = bpl;
    partials[2 * bid + 1] = bpa;
    __threadfence();
    int old = atomicAdd(counter, 1);
    slast = (old == 255);
  }
  __syncthreads();
  if (slast) {
    __threadfence();
    float* s1 = (float*)hist;   // reuse LDS
    float* s2 = s1 + 256;
    if (tid < 256) { s1[tid] = partials[2 * tid]; s2[tid] = partials[2 * tid + 1]; }
    __syncthreads();
    for (int off = 128; off > 0; off >>= 1) {
      if (tid < off) { s1[tid] += s1[tid + off]; s2[tid] += s2[tid + off]; }
      __syncthreads();
    }
    if (tid == 0) { out[0] = s1[0]; out[1] = s2[0]; }
  }
}

extern "C" void kernel_launch(void* const* d_in, const int* in_sizes, int n_in,
                              void* d_out, int out_size, void* d_ws, size_t ws_size,
                              hipStream_t stream) {
  const float* feat = (const float*)d_in[0];  // feat_proj [B,C,T]
  const void*  mask = d_in[1];                // mask [B,T] bool
  const float* ctx  = (const float*)d_in[2];  // context_output [B,C,T]
  float* out = (float*)d_out;

  char* ws = (char*)d_ws;
  u16*   MC       = (u16*)ws;                      // 2 MB [B,M,C] bf16 (ctx)
  u16*   MF       = (u16*)(ws + (2u << 20));       // 2 MB [B,M,C] bf16 (feat)
  float* partials = (float*)(ws + (4u << 20));     // 256*2 f32
  int*   counter  = (int*)(ws + (4u << 20) + 4096);

  dim3 gc(NT / 128, NB * 2);
  k_compact<<<gc, 256, 0, stream>>>(ctx, feat, mask, MC, MF, counter);

  k_fused<<<NB * 32, 512, 0, stream>>>(MC, MF, partials, counter, out);
}